// Round 1
// baseline (189.988 us; speedup 1.0000x reference)
//
#include <hip/hip_runtime.h>
#include <hip/hip_bf16.h>

// Flash attention fwd, causal + key-padding, B=4 S=4096 D=64, fp32 in/out,
// bf16 MFMA compute (threshold 7.7e-2 permits). Scale 1/8 folded into Q
// (exact: power of two). Masked scores -> -1e30 (exp underflows to 0,
// matching ref's (dot-1e10)/8 path).

#define S_LEN 4096
#define D_DIM 64
#define NBATCH 4
#define QBLK 64
#define KVBLK 64

typedef __attribute__((ext_vector_type(4))) float f32x4;
typedef __attribute__((ext_vector_type(8))) short s16x8;
typedef __attribute__((ext_vector_type(4))) short s16x4;

__device__ __forceinline__ unsigned short f2bf(float f) {
  unsigned u = __builtin_bit_cast(unsigned, f);
  u += 0x7FFFu + ((u >> 16) & 1u);   // RNE
  return (unsigned short)(u >> 16);
}

__global__ __launch_bounds__(256, 1) void fattn_kernel(
    const float* __restrict__ Qg, const float* __restrict__ Kg,
    const float* __restrict__ Vg, const unsigned char* __restrict__ Pad,
    float* __restrict__ Og)
{
  const int blk = blockIdx.x;
  const int b   = blk >> 6;          // batch
  const int qt  = blk & 63;          // q-tile index
  const int q0  = qt * QBLK;
  const int tid = threadIdx.x;
  const int w   = tid >> 6;          // wave 0..3, owns q rows [q0+16w, q0+16w+16)
  const int l   = tid & 63;
  const int c   = l & 15;            // MFMA col / frag row
  const int g   = l >> 4;            // lane group 0..3

  __shared__ short Ksh[KVBLK * D_DIM];      // [n][d] bf16, XOR-swizzled rows
  __shared__ short Vtsh[D_DIM * KVBLK];     // [d][n] bf16 (V transposed), swizzled
  __shared__ short Psh[4][16 * 72];         // per-wave P tile, stride 72 (16B-aligned, anti-conflict)
  __shared__ float bias[KVBLK];             // padding bias per key column

  // ---- Q fragments in registers, pre-scaled by 1/8 ----
  s16x8 qf[2];
  {
    const int qrow = q0 + 16 * w + c;       // A-frag row = lane&15
    const float* qp = Qg + ((size_t)(b * S_LEN + qrow)) * D_DIM + 8 * g;
    #pragma unroll
    for (int ck = 0; ck < 2; ++ck)
      #pragma unroll
      for (int j = 0; j < 8; ++j)
        qf[ck][j] = (short)f2bf(qp[32 * ck + j] * 0.125f);
  }

  f32x4 acc[4];
  #pragma unroll
  for (int td = 0; td < 4; ++td) acc[td] = (f32x4){0.f, 0.f, 0.f, 0.f};
  float mrow[4] = {-INFINITY, -INFINITY, -INFINITY, -INFINITY};
  float lrow[4] = {0.f, 0.f, 0.f, 0.f};

  const int nt = qt + 1;                    // causal: KV tiles 0..qt

  for (int t = 0; t < nt; ++t) {
    const int kv0 = t * KVBLK;

    // ---- stage K (row-major) and V (transposed), fp32->bf16, swizzled ----
    #pragma unroll
    for (int i = 0; i < 4; ++i) {
      const int flat = tid + 256 * i;       // 0..1023 = 64 rows * 16 float4
      const int n  = flat >> 4;
      const int d0 = (flat & 15) << 2;
      const size_t goff = ((size_t)(b * S_LEN + kv0 + n)) * D_DIM + d0;
      const float4 kv = *(const float4*)(Kg + goff);
      const float4 vv = *(const float4*)(Vg + goff);
      s16x4 kb;
      kb[0] = (short)f2bf(kv.x); kb[1] = (short)f2bf(kv.y);
      kb[2] = (short)f2bf(kv.z); kb[3] = (short)f2bf(kv.w);
      *(s16x4*)((char*)Ksh + n * 128 + ((d0 * 2) ^ ((n & 7) << 4))) = kb;
      const float vvv[4] = {vv.x, vv.y, vv.z, vv.w};
      #pragma unroll
      for (int j = 0; j < 4; ++j) {
        const int d = d0 + j;
        *(short*)((char*)Vtsh + d * 128 + ((2 * n) ^ ((d & 7) << 4))) = (short)f2bf(vvv[j]);
      }
    }
    if (tid < KVBLK)
      bias[tid] = Pad[(size_t)b * S_LEN + kv0 + tid] ? -1e30f : 0.0f;
    __syncthreads();

    // ---- S = (Q/8) K^T : 4 n-tiles of 16x16, K-dim d=64 in 2 chunks ----
    f32x4 s[4];
    #pragma unroll
    for (int tt = 0; tt < 4; ++tt) {
      f32x4 a = (f32x4){0.f, 0.f, 0.f, 0.f};
      #pragma unroll
      for (int ck = 0; ck < 2; ++ck) {
        const s16x8 kf = *(const s16x8*)((char*)Ksh + (16 * tt + c) * 128 +
                                         ((64 * ck + 16 * g) ^ ((c & 7) << 4)));
        a = __builtin_amdgcn_mfma_f32_16x16x32_bf16(qf[ck], kf, a, 0, 0, 0);
      }
      s[tt] = a;
    }

    // ---- padding bias (all tiles) + causal mask (diagonal tile only) ----
    const bool lastt = (t == nt - 1);
    #pragma unroll
    for (int tt = 0; tt < 4; ++tt) {
      const float bb = bias[16 * tt + c];
      #pragma unroll
      for (int j = 0; j < 4; ++j) {
        float sv = s[tt][j] + bb;
        if (lastt && (kv0 + 16 * tt + c > q0 + 16 * w + 4 * g + j)) sv = -1e30f;
        s[tt][j] = sv;
      }
    }

    // ---- online softmax (D-layout: row = 4g+j lives in 16-lane group g) ----
    #pragma unroll
    for (int j = 0; j < 4; ++j) {
      float v = fmaxf(fmaxf(s[0][j], s[1][j]), fmaxf(s[2][j], s[3][j]));
      #pragma unroll
      for (int off = 1; off < 16; off <<= 1) v = fmaxf(v, __shfl_xor(v, off));
      const float mn = fmaxf(mrow[j], v);
      const float corr = __expf(mrow[j] - mn);
      mrow[j] = mn;
      float rs = 0.f;
      #pragma unroll
      for (int tt = 0; tt < 4; ++tt) {
        const float p = __expf(s[tt][j] - mn);
        rs += p;
        Psh[w][(4 * g + j) * 72 + 16 * tt + c] = (short)f2bf(p);
      }
      #pragma unroll
      for (int off = 1; off < 16; off <<= 1) rs += __shfl_xor(rs, off);
      lrow[j] = lrow[j] * corr + rs;
      #pragma unroll
      for (int td = 0; td < 4; ++td) acc[td][j] *= corr;
    }

    // ---- O += P V : A-frag = P rows (LDS round-trip), B-frag = V^T rows ----
    #pragma unroll
    for (int ck = 0; ck < 2; ++ck) {
      const s16x8 pf = *(const s16x8*)((char*)&Psh[w][0] + c * 144 + 64 * ck + 16 * g);
      #pragma unroll
      for (int td = 0; td < 4; ++td) {
        const s16x8 vf = *(const s16x8*)((char*)Vtsh + (16 * td + c) * 128 +
                                         ((64 * ck + 16 * g) ^ ((c & 7) << 4)));
        acc[td] = __builtin_amdgcn_mfma_f32_16x16x32_bf16(pf, vf, acc[td], 0, 0, 0);
      }
    }
    __syncthreads();
  }

  // ---- epilogue: O = acc / l ----
  #pragma unroll
  for (int j = 0; j < 4; ++j) {
    const float inv = 1.0f / lrow[j];
    const int qrow = q0 + 16 * w + 4 * g + j;
    #pragma unroll
    for (int td = 0; td < 4; ++td)
      Og[((size_t)(b * S_LEN + qrow)) * D_DIM + 16 * td + c] = acc[td][j] * inv;
  }
}

extern "C" void kernel_launch(void* const* d_in, const int* in_sizes, int n_in,
                              void* d_out, int out_size, void* d_ws, size_t ws_size,
                              hipStream_t stream) {
  const float* Q = (const float*)d_in[0];
  const float* K = (const float*)d_in[1];
  const float* V = (const float*)d_in[2];
  const unsigned char* P = (const unsigned char*)d_in[3];
  float* O = (float*)d_out;
  dim3 grid(NBATCH * (S_LEN / QBLK));
  dim3 block(256);
  hipLaunchKernelGGL(fattn_kernel, grid, block, 0, stream, Q, K, V, P, O);
}

// Round 2
// 89.719 us; speedup vs baseline: 2.1176x; 2.1176x over previous
//
#include <hip/hip_runtime.h>
#include <hip/hip_bf16.h>

// Flash attention fwd, causal + key-padding, B=4 S=4096 D=64, fp32 in/out,
// bf16 MFMA compute. Scale 1/8 folded into Q (exact). Masked -> -1e30.
//
// Round 2: split-KV (flash-decoding). Partial kernel over (b, qtile, chunk)
// writes unnormalized O + (m,l) per row to d_ws; merge kernel combines.
// Fixes the structural parallelism cap (1024 waves = 1/SIMD) seen in round 1
// (Occupancy 6%, MfmaUtil 1.4%).

#define S_LEN 4096
#define D_DIM 64
#define NBATCH 4
#define QBLK 64
#define KVBLK 64
#define SLOT_F 4224   // 64*64 O + 64 m + 64 l floats per partial slot

typedef __attribute__((ext_vector_type(4))) float f32x4;
typedef __attribute__((ext_vector_type(8))) short s16x8;
typedef __attribute__((ext_vector_type(4))) short s16x4;

__device__ __forceinline__ unsigned short f2bf(float f) {
  unsigned u = __builtin_bit_cast(unsigned, f);
  u += 0x7FFFu + ((u >> 16) & 1u);   // RNE
  return (unsigned short)(u >> 16);
}

__global__ __launch_bounds__(256, 1) void fattn_partial(
    const float* __restrict__ Qg, const float* __restrict__ Kg,
    const float* __restrict__ Vg, const unsigned char* __restrict__ Pad,
    float* __restrict__ Og, float* __restrict__ Ws, int nchunk)
{
  // XCD-aware swizzle: consecutive logical blocks land on the same XCD
  // (HW round-robins blockIdx across 8 XCDs; grid is divisible by 8).
  const int N  = gridDim.x;
  const int wg = blockIdx.x;
  const int L  = (wg & 7) * (N >> 3) + (wg >> 3);

  const int ci  = L % nchunk;
  const int qtb = L / nchunk;        // (b*64 + qt)
  const int qt  = qtb & 63;
  const int b   = qtb >> 6;
  const int q0  = qt * QBLK;

  const int ntt = qt + 1;                        // causal tile count
  const int cw  = (ntt + nchunk - 1) / nchunk;   // tiles per chunk
  const int t0  = ci * cw;
  const int t1  = (t0 + cw < ntt) ? (t0 + cw) : ntt;
  if (t0 >= t1) return;                          // empty chunk

  const int tid = threadIdx.x;
  const int w   = tid >> 6;          // wave 0..3 -> q rows [16w,16w+16)
  const int l   = tid & 63;
  const int c   = l & 15;
  const int g   = l >> 4;

  __shared__ short Ksh[KVBLK * D_DIM];      // [n][d] bf16, XOR-swizzled rows
  __shared__ short Vtsh[D_DIM * KVBLK];     // [d][n] bf16 (V^T), swizzled
  __shared__ short Psh[4][16 * 72];         // per-wave P tile, stride 72
  __shared__ float bias[KVBLK];

  // Q fragments, pre-scaled by 1/8
  s16x8 qf[2];
  {
    const int qrow = q0 + 16 * w + c;
    const float* qp = Qg + ((size_t)(b * S_LEN + qrow)) * D_DIM + 8 * g;
    #pragma unroll
    for (int ck = 0; ck < 2; ++ck)
      #pragma unroll
      for (int j = 0; j < 8; ++j)
        qf[ck][j] = (short)f2bf(qp[32 * ck + j] * 0.125f);
  }

  f32x4 acc[4];
  #pragma unroll
  for (int td = 0; td < 4; ++td) acc[td] = (f32x4){0.f, 0.f, 0.f, 0.f};
  float mrow[4] = {-INFINITY, -INFINITY, -INFINITY, -INFINITY};
  float lrow[4] = {0.f, 0.f, 0.f, 0.f};

  for (int t = t0; t < t1; ++t) {
    const int kv0 = t * KVBLK;

    // stage K (row-major) and V (transposed), fp32->bf16, swizzled
    #pragma unroll
    for (int i = 0; i < 4; ++i) {
      const int flat = tid + 256 * i;
      const int n  = flat >> 4;
      const int d0 = (flat & 15) << 2;
      const size_t goff = ((size_t)(b * S_LEN + kv0 + n)) * D_DIM + d0;
      const float4 kv = *(const float4*)(Kg + goff);
      const float4 vv = *(const float4*)(Vg + goff);
      s16x4 kb;
      kb[0] = (short)f2bf(kv.x); kb[1] = (short)f2bf(kv.y);
      kb[2] = (short)f2bf(kv.z); kb[3] = (short)f2bf(kv.w);
      *(s16x4*)((char*)Ksh + n * 128 + ((d0 * 2) ^ ((n & 7) << 4))) = kb;
      const float vvv[4] = {vv.x, vv.y, vv.z, vv.w};
      #pragma unroll
      for (int j = 0; j < 4; ++j) {
        const int d = d0 + j;
        *(short*)((char*)Vtsh + d * 128 + ((2 * n) ^ ((d & 7) << 4))) = (short)f2bf(vvv[j]);
      }
    }
    if (tid < KVBLK)
      bias[tid] = Pad[(size_t)b * S_LEN + kv0 + tid] ? -1e30f : 0.0f;
    __syncthreads();

    // S = (Q/8) K^T
    f32x4 s[4];
    #pragma unroll
    for (int tt = 0; tt < 4; ++tt) {
      f32x4 a = (f32x4){0.f, 0.f, 0.f, 0.f};
      #pragma unroll
      for (int ck = 0; ck < 2; ++ck) {
        const s16x8 kf = *(const s16x8*)((char*)Ksh + (16 * tt + c) * 128 +
                                         ((64 * ck + 16 * g) ^ ((c & 7) << 4)));
        a = __builtin_amdgcn_mfma_f32_16x16x32_bf16(qf[ck], kf, a, 0, 0, 0);
      }
      s[tt] = a;
    }

    // padding bias + causal mask (diagonal tile only)
    const bool lastt = (t == ntt - 1);
    #pragma unroll
    for (int tt = 0; tt < 4; ++tt) {
      const float bb = bias[16 * tt + c];
      #pragma unroll
      for (int j = 0; j < 4; ++j) {
        float sv = s[tt][j] + bb;
        if (lastt && (kv0 + 16 * tt + c > q0 + 16 * w + 4 * g + j)) sv = -1e30f;
        s[tt][j] = sv;
      }
    }

    // online softmax (row = 4g+j within 16-lane group g)
    #pragma unroll
    for (int j = 0; j < 4; ++j) {
      float v = fmaxf(fmaxf(s[0][j], s[1][j]), fmaxf(s[2][j], s[3][j]));
      #pragma unroll
      for (int off = 1; off < 16; off <<= 1) v = fmaxf(v, __shfl_xor(v, off));
      const float mn = fmaxf(mrow[j], v);
      const float corr = __expf(mrow[j] - mn);
      mrow[j] = mn;
      float rs = 0.f;
      #pragma unroll
      for (int tt = 0; tt < 4; ++tt) {
        const float p = __expf(s[tt][j] - mn);
        rs += p;
        Psh[w][(4 * g + j) * 72 + 16 * tt + c] = (short)f2bf(p);
      }
      #pragma unroll
      for (int off = 1; off < 16; off <<= 1) rs += __shfl_xor(rs, off);
      lrow[j] = lrow[j] * corr + rs;
      #pragma unroll
      for (int td = 0; td < 4; ++td) acc[td][j] *= corr;
    }

    // O += P V
    #pragma unroll
    for (int ck = 0; ck < 2; ++ck) {
      const s16x8 pf = *(const s16x8*)((char*)&Psh[w][0] + c * 144 + 64 * ck + 16 * g);
      #pragma unroll
      for (int td = 0; td < 4; ++td) {
        const s16x8 vf = *(const s16x8*)((char*)Vtsh + (16 * td + c) * 128 +
                                         ((64 * ck + 16 * g) ^ ((c & 7) << 4)));
        acc[td] = __builtin_amdgcn_mfma_f32_16x16x32_bf16(pf, vf, acc[td], 0, 0, 0);
      }
    }
    __syncthreads();
  }

  // epilogue
  if (nchunk == 1) {
    #pragma unroll
    for (int j = 0; j < 4; ++j) {
      const float inv = 1.0f / lrow[j];
      const int qrow = q0 + 16 * w + 4 * g + j;
      #pragma unroll
      for (int td = 0; td < 4; ++td)
        Og[((size_t)(b * S_LEN + qrow)) * D_DIM + 16 * td + c] = acc[td][j] * inv;
    }
  } else {
    float* slot = Ws + (size_t)(qtb * nchunk + ci) * SLOT_F;
    #pragma unroll
    for (int j = 0; j < 4; ++j) {
      const int row = 16 * w + 4 * g + j;
      #pragma unroll
      for (int td = 0; td < 4; ++td)
        slot[row * 64 + 16 * td + c] = acc[td][j];
      if (c == 0) {
        slot[4096 + row] = mrow[j];
        slot[4160 + row] = lrow[j];
      }
    }
  }
}

__global__ __launch_bounds__(256, 1) void fattn_merge(
    const float* __restrict__ Ws, float* __restrict__ Og, int nchunk)
{
  const int qtb = blockIdx.x;
  const int qt  = qtb & 63;
  const int b   = qtb >> 6;
  const int tid = threadIdx.x;
  const int r   = tid >> 2;          // q row within tile
  const int d0  = (tid & 3) << 4;    // 16 d-elems per thread

  const int ntt = qt + 1;
  const int cw  = (ntt + nchunk - 1) / nchunk;
  const int nvalid = (ntt + cw - 1) / cw;   // valid chunks are contiguous from 0

  const float* base = Ws + (size_t)qtb * nchunk * SLOT_F;

  float mstar = -INFINITY;
  for (int ci = 0; ci < nvalid; ++ci)
    mstar = fmaxf(mstar, base[(size_t)ci * SLOT_F + 4096 + r]);

  float lsum = 0.f;
  float o[16];
  #pragma unroll
  for (int k = 0; k < 16; ++k) o[k] = 0.f;

  for (int ci = 0; ci < nvalid; ++ci) {
    const float* slot = base + (size_t)ci * SLOT_F;
    const float wgt = __expf(slot[4096 + r] - mstar);
    lsum += wgt * slot[4160 + r];
    #pragma unroll
    for (int k = 0; k < 4; ++k) {
      const float4 ov = *(const float4*)(slot + r * 64 + d0 + 4 * k);
      o[4 * k + 0] += wgt * ov.x;
      o[4 * k + 1] += wgt * ov.y;
      o[4 * k + 2] += wgt * ov.z;
      o[4 * k + 3] += wgt * ov.w;
    }
  }

  const float inv = 1.0f / lsum;
  float* op = Og + ((size_t)(b * S_LEN + qt * QBLK + r)) * D_DIM + d0;
  #pragma unroll
  for (int k = 0; k < 4; ++k) {
    float4 ov;
    ov.x = o[4 * k + 0] * inv;
    ov.y = o[4 * k + 1] * inv;
    ov.z = o[4 * k + 2] * inv;
    ov.w = o[4 * k + 3] * inv;
    *(float4*)(op + 4 * k) = ov;
  }
}

extern "C" void kernel_launch(void* const* d_in, const int* in_sizes, int n_in,
                              void* d_out, int out_size, void* d_ws, size_t ws_size,
                              hipStream_t stream) {
  const float* Q = (const float*)d_in[0];
  const float* K = (const float*)d_in[1];
  const float* V = (const float*)d_in[2];
  const unsigned char* P = (const unsigned char*)d_in[3];
  float* O  = (float*)d_out;
  float* Ws = (float*)d_ws;

  const size_t slot_bytes = (size_t)SLOT_F * 4;
  int nchunk = 1;
  if (ws_size >= (size_t)NBATCH * 64 * 4 * slot_bytes)      nchunk = 4;
  else if (ws_size >= (size_t)NBATCH * 64 * 2 * slot_bytes) nchunk = 2;

  dim3 grid(NBATCH * (S_LEN / QBLK) * nchunk);
  dim3 block(256);
  hipLaunchKernelGGL(fattn_partial, grid, block, 0, stream, Q, K, V, P, O, Ws, nchunk);
  if (nchunk > 1) {
    dim3 mgrid(NBATCH * (S_LEN / QBLK));
    hipLaunchKernelGGL(fattn_merge, mgrid, block, 0, stream, Ws, O, nchunk);
  }
}

// Round 3
// 67.705 us; speedup vs baseline: 2.8061x; 1.3251x over previous
//
#include <hip/hip_runtime.h>
#include <hip/hip_bf16.h>

// Flash attention fwd, causal + key-padding, B=4 S=4096 D=64, fp32 in/out,
// bf16 MFMA compute. Scale 1/8 folded into Q (exact). Masked -> -1e30.
//
// Round 3: (a) conflict-free V^T staging via in-register 4x4 transpose
// (round 1/2 had 8-way-conflicted b16 scatter: 7.7M conflict cycles),
// (b) heavy-blocks-first dispatch order (kill the qt=63 tail),
// (c) nchunk up to 8, (d) row-sum l via MFMA ones-column (no shfl sum
// reduce), (e) register prefetch of next K/V tile under compute.

#define S_LEN 4096
#define D_DIM 64
#define NBATCH 4
#define QBLK 64
#define KVBLK 64
#define SLOT_F 4224   // 64*64 O + 64 m + 64 l floats per partial slot

typedef __attribute__((ext_vector_type(4))) float f32x4;
typedef __attribute__((ext_vector_type(8))) short s16x8;
typedef __attribute__((ext_vector_type(4))) short s16x4;
typedef __attribute__((ext_vector_type(2))) unsigned int u32x2;

#define FK(n) ((((n) ^ ((n) >> 3)) & 7) << 4)   // K row swizzle (byte)
#define FV(d) (((d) & 7) << 4)                  // V^T row swizzle (byte)

__device__ __forceinline__ unsigned short f2bfu(float f) {
  return __builtin_bit_cast(unsigned short, __float2bfloat16(f));
}
__device__ __forceinline__ unsigned pk2(float a, float b) {
  return (unsigned)f2bfu(a) | ((unsigned)f2bfu(b) << 16);
}

__global__ __launch_bounds__(256, 4) void fattn_partial(
    const float* __restrict__ Qg, const float* __restrict__ Kg,
    const float* __restrict__ Vg, const unsigned char* __restrict__ Pad,
    float* __restrict__ Og, float* __restrict__ Ws, int nchunk)
{
  // Heavy-first dispatch: rank 0 = qt 63 (most KV tiles).
  const int wid = blockIdx.x;
  const int r   = wid / nchunk;
  const int ci  = wid % nchunk;
  const int qt  = 63 - (r >> 2);
  const int b   = r & 3;
  const int qtb = b * 64 + qt;
  const int q0  = qt * QBLK;

  const int ntt = qt + 1;                        // causal tile count
  const int cw  = (ntt + nchunk - 1) / nchunk;   // tiles per chunk
  const int t0  = ci * cw;
  const int t1  = (t0 + cw < ntt) ? (t0 + cw) : ntt;
  if (t0 >= t1) return;                          // empty chunk

  const int tid = threadIdx.x;
  const int w   = tid >> 6;          // wave 0..3 -> q rows [16w,16w+16)
  const int l   = tid & 63;
  const int c   = l & 15;
  const int g   = l >> 4;

  // staging roles: quad sq transposes a 4x4 V block held by adjacent lanes
  const int sq  = l & 3;
  const int sm  = (l >> 2) & 3;
  const int sc2 = l >> 4;
  const int snb = 4 * w + 16 * sc2;  // n-chunk base (mult of 4)

  __shared__ short Ksh[KVBLK * D_DIM];      // [n][d] bf16, FK-swizzled rows
  __shared__ short Vtsh[D_DIM * KVBLK];     // [d][n] bf16 (V^T), FV-swizzled
  __shared__ short Psh[4][16 * 72];         // per-wave P tile, stride 72
  __shared__ float bias[KVBLK];

  // Q fragments, pre-scaled by 1/8
  s16x8 qf[2];
  {
    const int qrow = q0 + 16 * w + c;
    const float* qp = Qg + ((size_t)(b * S_LEN + qrow)) * D_DIM + 8 * g;
    #pragma unroll
    for (int ck = 0; ck < 2; ++ck)
      #pragma unroll
      for (int j = 0; j < 8; ++j)
        qf[ck][j] = (short)f2bfu(qp[32 * ck + j] * 0.125f);
  }

  s16x8 ones;
  #pragma unroll
  for (int j = 0; j < 8; ++j) ones[j] = (short)0x3F80;  // bf16 1.0

  f32x4 acc[4];
  #pragma unroll
  for (int td = 0; td < 4; ++td) acc[td] = (f32x4){0.f, 0.f, 0.f, 0.f};
  f32x4 lacc = (f32x4){0.f, 0.f, 0.f, 0.f};
  float mrow[4] = {-INFINITY, -INFINITY, -INFINITY, -INFINITY};

  float4 kpre[4], vpre[4];
  unsigned char padpre;

#define LOAD_TILE(T) do {                                                   \
    const int kv0_ = (T) * KVBLK;                                           \
    _Pragma("unroll")                                                       \
    for (int s_ = 0; s_ < 4; ++s_) {                                        \
      const int d0_ = 16 * s_ + 4 * sm;                                     \
      const size_t goff_ =                                                  \
          ((size_t)(b * S_LEN + kv0_ + snb + sq)) * D_DIM + d0_;            \
      kpre[s_] = *(const float4*)(Kg + goff_);                              \
      vpre[s_] = *(const float4*)(Vg + goff_);                              \
    }                                                                       \
    padpre = (tid < KVBLK) ? Pad[(size_t)b * S_LEN + kv0_ + tid]            \
                           : (unsigned char)0;                              \
  } while (0)

  LOAD_TILE(t0);

  for (int t = t0; t < t1; ++t) {
    // ---- stage prefetched K (direct) / V (reg 4x4 transpose) to LDS ----
    #pragma unroll
    for (int s = 0; s < 4; ++s) {
      const float4 kx = kpre[s];
      const float4 vx = vpre[s];
      const int d0 = 16 * s + 4 * sm;
      const int nk = snb + sq;
      s16x4 kb;
      kb[0] = (short)f2bfu(kx.x); kb[1] = (short)f2bfu(kx.y);
      kb[2] = (short)f2bfu(kx.z); kb[3] = (short)f2bfu(kx.w);
      *(s16x4*)((char*)Ksh + nk * 128 + ((2 * d0) ^ FK(nk))) = kb;

      unsigned u0 = pk2(vx.x, vx.y), u1 = pk2(vx.z, vx.w);
      unsigned x  = (sq & 2) ? u0 : u1;
      unsigned y  = __shfl_xor(x, 2);
      unsigned A0 = (sq & 2) ? y : u0;
      unsigned A1 = (sq & 2) ? u1 : y;
      unsigned z0 = __shfl_xor(A0, 1);
      unsigned z1 = __shfl_xor(A1, 1);
      unsigned o0, o1;
      if (sq & 1) { o0 = (z0 >> 16) | (A0 & 0xFFFF0000u);
                    o1 = (z1 >> 16) | (A1 & 0xFFFF0000u); }
      else        { o0 = (A0 & 0xFFFFu) | (z0 << 16);
                    o1 = (A1 & 0xFFFFu) | (z1 << 16); }
      const int dv = d0 + sq;
      u32x2 vv2; vv2[0] = o0; vv2[1] = o1;
      *(u32x2*)((char*)Vtsh + dv * 128 + ((2 * snb) ^ FV(dv))) = vv2;
    }
    if (tid < KVBLK) bias[tid] = padpre ? -1e30f : 0.0f;
    __syncthreads();

    // ---- prefetch next tile (latency hides under compute below) ----
    if (t + 1 < t1) LOAD_TILE(t + 1);

    // ---- S = (Q/8) K^T ----
    f32x4 s[4];
    #pragma unroll
    for (int tt = 0; tt < 4; ++tt) {
      f32x4 a = (f32x4){0.f, 0.f, 0.f, 0.f};
      #pragma unroll
      for (int ck = 0; ck < 2; ++ck) {
        const int nk2 = 16 * tt + c;
        const s16x8 kf = *(const s16x8*)((char*)Ksh + nk2 * 128 +
                                         ((64 * ck + 16 * g) ^ FK(nk2)));
        a = __builtin_amdgcn_mfma_f32_16x16x32_bf16(qf[ck], kf, a, 0, 0, 0);
      }
      s[tt] = a;
    }

    // ---- padding bias + causal mask (diagonal tile only) ----
    const bool lastt = (t == ntt - 1);
    #pragma unroll
    for (int tt = 0; tt < 4; ++tt) {
      const int kv0 = t * KVBLK;
      const float bb = bias[16 * tt + c];
      #pragma unroll
      for (int j = 0; j < 4; ++j) {
        float sv = s[tt][j] + bb;
        if (lastt && (kv0 + 16 * tt + c > q0 + 16 * w + 4 * g + j)) sv = -1e30f;
        s[tt][j] = sv;
      }
    }

    // ---- online softmax; row sums come from the ones-column MFMA ----
    #pragma unroll
    for (int j = 0; j < 4; ++j) {
      float v = fmaxf(fmaxf(s[0][j], s[1][j]), fmaxf(s[2][j], s[3][j]));
      #pragma unroll
      for (int off = 1; off < 16; off <<= 1) v = fmaxf(v, __shfl_xor(v, off));
      const float mn = fmaxf(mrow[j], v);
      const float corr = __expf(mrow[j] - mn);
      mrow[j] = mn;
      #pragma unroll
      for (int tt = 0; tt < 4; ++tt) {
        const float p = __expf(s[tt][j] - mn);
        Psh[w][(4 * g + j) * 72 + 16 * tt + c] = (short)f2bfu(p);
      }
      lacc[j] *= corr;
      #pragma unroll
      for (int td = 0; td < 4; ++td) acc[td][j] *= corr;
    }

    // ---- O += P V ; l += P 1 ----
    #pragma unroll
    for (int ck = 0; ck < 2; ++ck) {
      const s16x8 pf = *(const s16x8*)((char*)&Psh[w][0] + c * 144 + 64 * ck + 16 * g);
      #pragma unroll
      for (int td = 0; td < 4; ++td) {
        const int dv = 16 * td + c;
        const s16x8 vf = *(const s16x8*)((char*)Vtsh + dv * 128 +
                                         ((64 * ck + 16 * g) ^ FV(dv)));
        acc[td] = __builtin_amdgcn_mfma_f32_16x16x32_bf16(pf, vf, acc[td], 0, 0, 0);
      }
      lacc = __builtin_amdgcn_mfma_f32_16x16x32_bf16(pf, ones, lacc, 0, 0, 0);
    }
    __syncthreads();
  }

  // ---- epilogue ----
  if (nchunk == 1) {
    #pragma unroll
    for (int j = 0; j < 4; ++j) {
      const float inv = 1.0f / lacc[j];
      const int qrow = q0 + 16 * w + 4 * g + j;
      #pragma unroll
      for (int td = 0; td < 4; ++td)
        Og[((size_t)(b * S_LEN + qrow)) * D_DIM + 16 * td + c] = acc[td][j] * inv;
    }
  } else {
    float* slot = Ws + (size_t)(qtb * nchunk + ci) * SLOT_F;
    #pragma unroll
    for (int j = 0; j < 4; ++j) {
      const int row = 16 * w + 4 * g + j;
      #pragma unroll
      for (int td = 0; td < 4; ++td)
        slot[row * 64 + 16 * td + c] = acc[td][j];
      if (c == 0) {
        slot[4096 + row] = mrow[j];
        slot[4160 + row] = lacc[j];
      }
    }
  }
}

__global__ __launch_bounds__(256, 4) void fattn_merge(
    const float* __restrict__ Ws, float* __restrict__ Og, int nchunk)
{
  const int qtb = blockIdx.x;
  const int qt  = qtb & 63;
  const int b   = qtb >> 6;
  const int tid = threadIdx.x;
  const int r   = tid >> 2;          // q row within tile
  const int d0  = (tid & 3) << 4;    // 16 d-elems per thread

  const int ntt = qt + 1;
  const int cw  = (ntt + nchunk - 1) / nchunk;
  const int nvalid = (ntt + cw - 1) / cw;   // valid chunks contiguous from 0

  const float* base = Ws + (size_t)qtb * nchunk * SLOT_F;

  float mstar = -INFINITY;
  for (int ci = 0; ci < nvalid; ++ci)
    mstar = fmaxf(mstar, base[(size_t)ci * SLOT_F + 4096 + r]);

  float lsum = 0.f;
  float o[16];
  #pragma unroll
  for (int k = 0; k < 16; ++k) o[k] = 0.f;

  for (int ci = 0; ci < nvalid; ++ci) {
    const float* slot = base + (size_t)ci * SLOT_F;
    const float wgt = __expf(slot[4096 + r] - mstar);
    lsum += wgt * slot[4160 + r];
    #pragma unroll
    for (int k = 0; k < 4; ++k) {
      const float4 ov = *(const float4*)(slot + r * 64 + d0 + 4 * k);
      o[4 * k + 0] += wgt * ov.x;
      o[4 * k + 1] += wgt * ov.y;
      o[4 * k + 2] += wgt * ov.z;
      o[4 * k + 3] += wgt * ov.w;
    }
  }

  const float inv = 1.0f / lsum;
  float* op = Og + ((size_t)(b * S_LEN + qt * QBLK + r)) * D_DIM + d0;
  #pragma unroll
  for (int k = 0; k < 4; ++k) {
    float4 ov;
    ov.x = o[4 * k + 0] * inv;
    ov.y = o[4 * k + 1] * inv;
    ov.z = o[4 * k + 2] * inv;
    ov.w = o[4 * k + 3] * inv;
    *(float4*)(op + 4 * k) = ov;
  }
}

extern "C" void kernel_launch(void* const* d_in, const int* in_sizes, int n_in,
                              void* d_out, int out_size, void* d_ws, size_t ws_size,
                              hipStream_t stream) {
  const float* Q = (const float*)d_in[0];
  const float* K = (const float*)d_in[1];
  const float* V = (const float*)d_in[2];
  const unsigned char* P = (const unsigned char*)d_in[3];
  float* O  = (float*)d_out;
  float* Ws = (float*)d_ws;

  const size_t slot_bytes = (size_t)SLOT_F * 4;
  int nchunk = 1;
  if      (ws_size >= (size_t)256 * 8 * slot_bytes) nchunk = 8;
  else if (ws_size >= (size_t)256 * 4 * slot_bytes) nchunk = 4;
  else if (ws_size >= (size_t)256 * 2 * slot_bytes) nchunk = 2;

  dim3 grid(NBATCH * (S_LEN / QBLK) * nchunk);
  dim3 block(256);
  hipLaunchKernelGGL(fattn_partial, grid, block, 0, stream, Q, K, V, P, O, Ws, nchunk);
  if (nchunk > 1) {
    dim3 mgrid(NBATCH * (S_LEN / QBLK));
    hipLaunchKernelGGL(fattn_merge, mgrid, block, 0, stream, Ws, O, nchunk);
  }
}

// Round 5
// 65.503 us; speedup vs baseline: 2.9005x; 1.0336x over previous
//
#include <hip/hip_runtime.h>
#include <hip/hip_bf16.h>

// Flash attention fwd, causal + key-padding, B=4 S=4096 D=64, fp32 in/out.
// Round 5: 32x32x16 swapped-operand MFMA (S^T = K·Q^T, O^T = V^T·P^T) with
// PERMUTATION-PROOF operand packing: P B-frag uses the MFMA C/D's native
// k-order (no cross-lane ops), V^T A-frag reads the same element->k map
// (two 8B LDS reads). Dot-product invariance => correct under any HW
// per-lane k-permutation. m/l half-merges via __shfl_xor(.,32).
// Split-KV (nchunk<=8), heavy-first dispatch, dbuf LDS, reg prefetch kept.

#define S_LEN 4096
#define D_DIM 64
#define NBATCH 4
#define QBLK 128
#define KVBLK 64
#define NQB (S_LEN / QBLK)                // 32 q-blocks per batch
#define SLOT_F (QBLK * D_DIM + 2 * QBLK)  // 8448 floats per partial slot

typedef __attribute__((ext_vector_type(16))) float f32x16;
typedef __attribute__((ext_vector_type(4))) float f32x4;
typedef __attribute__((ext_vector_type(8))) short s16x8;
typedef __attribute__((ext_vector_type(4))) short s16x4;
typedef __attribute__((ext_vector_type(2))) unsigned int u32x2;

#define FK(n) ((((n) ^ ((n) >> 3)) & 7) << 4)                    // K swizzle
#define FV(d) (((((d) & 7) << 4)) ^ ((((d) >> 3) & 1) << 3))     // V^T swizzle

__device__ __forceinline__ unsigned short f2bfu(float f) {
  return __builtin_bit_cast(unsigned short, __float2bfloat16(f));
}
__device__ __forceinline__ unsigned pk2(float a, float b) {
  return (unsigned)f2bfu(a) | ((unsigned)f2bfu(b) << 16);
}

__global__ __launch_bounds__(256, 3) void fattn_partial(
    const float* __restrict__ Qg, const float* __restrict__ Kg,
    const float* __restrict__ Vg, const unsigned char* __restrict__ Pad,
    float* __restrict__ Og, float* __restrict__ Ws, int nchunk)
{
  // Heavy-first dispatch: rank 0 = largest q-block index.
  const int wid = blockIdx.x;
  const int r   = wid / nchunk;
  const int ci  = wid % nchunk;
  const int Qb  = (NQB - 1) - (r >> 2);
  const int b   = r & 3;
  const int qbi = b * NQB + Qb;
  const int q0  = Qb * QBLK;

  const int ntt = 2 * Qb + 2;                    // causal: KV tiles needed
  const int cw  = (ntt + nchunk - 1) / nchunk;
  const int t0  = ci * cw;
  const int t1  = (t0 + cw < ntt) ? (t0 + cw) : ntt;
  if (t0 >= t1) return;

  const int tid = threadIdx.x;
  const int w   = tid >> 6;          // wave 0..3 -> q rows [q0+32w, q0+32w+32)
  const int l   = tid & 63;
  const int ql  = l & 31;            // q within wave tile
  const int hi  = l >> 5;
  const int qw0 = q0 + 32 * w;
  const int qa  = qw0 + ql;          // absolute q row for this lane

  // staging roles (cover 64 rows x 16 float4 with 256 threads)
  const int sq  = l & 3;
  const int sm  = (l >> 2) & 3;
  const int sc2 = l >> 4;
  const int snb = 4 * w + 16 * sc2;  // n-chunk base (multiple of 4)

  __shared__ short Ksh[2][KVBLK * D_DIM];   // [n][d] bf16, FK-swizzled
  __shared__ short Vtsh[2][D_DIM * KVBLK];  // [d][n] bf16 (V^T), FV-swizzled
  __shared__ float biassh[2][KVBLK];

  // ---- Q fragments (B-operand), pre-scaled by 1/8 ----
  s16x8 qf[4];
  {
    const float* qp = Qg + ((size_t)(b * S_LEN + qa)) * D_DIM + 8 * hi;
    #pragma unroll
    for (int dc = 0; dc < 4; ++dc)
      #pragma unroll
      for (int j = 0; j < 8; ++j)
        qf[dc][j] = (short)f2bfu(qp[16 * dc + j] * 0.125f);
  }

  f32x16 acc[2];
  #pragma unroll
  for (int dt = 0; dt < 2; ++dt)
    #pragma unroll
    for (int i = 0; i < 16; ++i) acc[dt][i] = 0.f;
  float mrow = -INFINITY;
  float lrow = 0.f;

  float4 kpre[4], vpre[4];
  unsigned char padpre;

#define LOAD_K(T) do {                                                       \
    const int kv0_ = (T) * KVBLK;                                            \
    _Pragma("unroll")                                                        \
    for (int s_ = 0; s_ < 4; ++s_) {                                         \
      const size_t go_ =                                                     \
          ((size_t)(b * S_LEN + kv0_ + snb + sq)) * D_DIM + 16 * s_ + 4 * sm;\
      kpre[s_] = *(const float4*)(Kg + go_);                                 \
    }                                                                        \
    padpre = (tid < KVBLK) ? Pad[(size_t)b * S_LEN + kv0_ + tid]             \
                           : (unsigned char)0;                               \
  } while (0)

#define LOAD_V(T) do {                                                       \
    const int kv0_ = (T) * KVBLK;                                            \
    _Pragma("unroll")                                                        \
    for (int s_ = 0; s_ < 4; ++s_) {                                         \
      const size_t go_ =                                                     \
          ((size_t)(b * S_LEN + kv0_ + snb + sq)) * D_DIM + 16 * s_ + 4 * sm;\
      vpre[s_] = *(const float4*)(Vg + go_);                                 \
    }                                                                        \
  } while (0)

#define STAGE(BUF) do {                                                      \
    _Pragma("unroll")                                                        \
    for (int s_ = 0; s_ < 4; ++s_) {                                         \
      const float4 kx = kpre[s_]; const float4 vx = vpre[s_];                \
      const int d0_ = 16 * s_ + 4 * sm; const int nk_ = snb + sq;            \
      s16x4 kb;                                                              \
      kb[0] = (short)f2bfu(kx.x); kb[1] = (short)f2bfu(kx.y);                \
      kb[2] = (short)f2bfu(kx.z); kb[3] = (short)f2bfu(kx.w);                \
      *(s16x4*)((char*)&Ksh[BUF][0] + nk_ * 128 + ((2 * d0_) ^ FK(nk_))) = kb;\
      unsigned u0 = pk2(vx.x, vx.y), u1 = pk2(vx.z, vx.w);                   \
      unsigned x_ = (sq & 2) ? u0 : u1;                                      \
      unsigned y_ = __shfl_xor(x_, 2);                                       \
      unsigned A0 = (sq & 2) ? y_ : u0;                                      \
      unsigned A1 = (sq & 2) ? u1 : y_;                                      \
      unsigned z0 = __shfl_xor(A0, 1);                                       \
      unsigned z1 = __shfl_xor(A1, 1);                                       \
      unsigned o0, o1;                                                       \
      if (sq & 1) { o0 = (z0 >> 16) | (A0 & 0xFFFF0000u);                    \
                    o1 = (z1 >> 16) | (A1 & 0xFFFF0000u); }                  \
      else        { o0 = (A0 & 0xFFFFu) | (z0 << 16);                        \
                    o1 = (A1 & 0xFFFFu) | (z1 << 16); }                      \
      const int dv_ = d0_ + sq;                                              \
      u32x2 vv2; vv2[0] = o0; vv2[1] = o1;                                   \
      *(u32x2*)((char*)&Vtsh[BUF][0] + dv_ * 128 + ((2 * snb) ^ FV(dv_))) = vv2;\
    }                                                                        \
    if (tid < KVBLK) biassh[BUF][tid] = padpre ? -1e30f : 0.0f;              \
  } while (0)

  LOAD_K(t0);
  LOAD_V(t0);
  STAGE(0);
  __syncthreads();
  int cb = 0;

  for (int t = t0; t < t1; ++t) {
    const int kv0 = t * KVBLK;
    const bool more = (t + 1 < t1);
    if (more) LOAD_K(t + 1);

    // ---- S^T = mfma(A=K, B=Q): col=lane&31=q, row=k ----
    f32x16 sv[2];
    #pragma unroll
    for (int kt = 0; kt < 2; ++kt) {
      f32x16 a;
      #pragma unroll
      for (int i = 0; i < 16; ++i) a[i] = 0.f;
      #pragma unroll
      for (int dc = 0; dc < 4; ++dc) {
        const int nr = 32 * kt + ql;
        const s16x8 kf = *(const s16x8*)((char*)&Ksh[cb][0] + nr * 128 +
                                         ((32 * dc + 16 * hi) ^ FK(nr)));
        a = __builtin_amdgcn_mfma_f32_32x32x16_bf16(kf, qf[dc], a, 0, 0, 0);
      }
      sv[kt] = a;
    }

    if (more) LOAD_V(t + 1);

    // ---- padding bias + causal mask (k = kv0+32kt+8r1+4hi+r0) ----
    #pragma unroll
    for (int kt = 0; kt < 2; ++kt) {
      const int kvt = kv0 + 32 * kt;
      const bool needm = (kvt + 31) > qw0;
      #pragma unroll
      for (int r1 = 0; r1 < 4; ++r1) {
        const f32x4 bb = *(const f32x4*)&biassh[cb][32 * kt + 8 * r1 + 4 * hi];
        #pragma unroll
        for (int r0 = 0; r0 < 4; ++r0) {
          float x = sv[kt][4 * r1 + r0] + bb[r0];
          if (needm && (kvt + 8 * r1 + 4 * hi + r0 > qa)) x = -1e30f;
          sv[kt][4 * r1 + r0] = x;
        }
      }
    }

    // ---- in-register online softmax (per-lane scalar m, l) ----
    float vm = sv[0][0];
    #pragma unroll
    for (int kt = 0; kt < 2; ++kt)
      #pragma unroll
      for (int i = 0; i < 16; ++i) vm = fmaxf(vm, sv[kt][i]);
    vm = fmaxf(vm, __shfl_xor(vm, 32));           // merge across hi halves
    const float mn   = fmaxf(mrow, vm);
    const float corr = __expf(mrow - mn);
    mrow = mn;
    float rs = 0.f;
    #pragma unroll
    for (int kt = 0; kt < 2; ++kt)
      #pragma unroll
      for (int i = 0; i < 16; ++i) {
        const float p = __expf(sv[kt][i] - mn);
        sv[kt][i] = p;
        rs += p;
      }
    lrow = lrow * corr + rs;                      // own half-sum only
    #pragma unroll
    for (int dt = 0; dt < 2; ++dt)
      #pragma unroll
      for (int i = 0; i < 16; ++i) acc[dt][i] *= corr;

    // ---- O^T += mfma(A=V^T, B=P) ----
    // P B-frag in C/D-native k-order: elem j <-> k = 4hi+(j&3)+8*(j>>2).
    // V^T A-frag reads the SAME element->k map (two 8B LDS reads), so the
    // contraction is correct under any HW per-lane k-permutation.
    #pragma unroll
    for (int sk = 0; sk < 4; ++sk) {
      const int kt = sk >> 1, rb = 8 * (sk & 1);
      union { unsigned u[4]; s16x8 v; } pb;
      pb.u[0] = pk2(sv[kt][rb + 0], sv[kt][rb + 1]);
      pb.u[1] = pk2(sv[kt][rb + 2], sv[kt][rb + 3]);
      pb.u[2] = pk2(sv[kt][rb + 4], sv[kt][rb + 5]);
      pb.u[3] = pk2(sv[kt][rb + 6], sv[kt][rb + 7]);
      #pragma unroll
      for (int dt = 0; dt < 2; ++dt) {
        const int dr = 32 * dt + ql;
        const char* vrow = (char*)&Vtsh[cb][0] + dr * 128;
        const s16x4 v0 = *(const s16x4*)(vrow + ((32 * sk + 8 * hi) ^ FV(dr)));
        const s16x4 v1 = *(const s16x4*)(vrow + ((32 * sk + 16 + 8 * hi) ^ FV(dr)));
        s16x8 vf;
        vf[0] = v0[0]; vf[1] = v0[1]; vf[2] = v0[2]; vf[3] = v0[3];
        vf[4] = v1[0]; vf[5] = v1[1]; vf[6] = v1[2]; vf[7] = v1[3];
        acc[dt] = __builtin_amdgcn_mfma_f32_32x32x16_bf16(vf, pb.v, acc[dt], 0, 0, 0);
      }
    }

    if (more) STAGE(cb ^ 1);
    __syncthreads();
    cb ^= 1;
  }

  // ---- epilogue: merge l across hi halves; write O^T-layout rows ----
  const float lt = lrow + __shfl_xor(lrow, 32);

  if (nchunk == 1) {
    const float inv = 1.0f / lt;
    #pragma unroll
    for (int dt = 0; dt < 2; ++dt)
      #pragma unroll
      for (int r1 = 0; r1 < 4; ++r1) {
        f32x4 o;
        #pragma unroll
        for (int r0 = 0; r0 < 4; ++r0) o[r0] = acc[dt][4 * r1 + r0] * inv;
        *(f32x4*)(Og + ((size_t)(b * S_LEN + qa)) * D_DIM +
                  32 * dt + 8 * r1 + 4 * hi) = o;
      }
  } else {
    float* slot = Ws + (size_t)(qbi * nchunk + ci) * SLOT_F;
    const int row = 32 * w + ql;
    #pragma unroll
    for (int dt = 0; dt < 2; ++dt)
      #pragma unroll
      for (int r1 = 0; r1 < 4; ++r1) {
        f32x4 o;
        #pragma unroll
        for (int r0 = 0; r0 < 4; ++r0) o[r0] = acc[dt][4 * r1 + r0];
        *(f32x4*)(slot + row * 64 + 32 * dt + 8 * r1 + 4 * hi) = o;
      }
    if (hi == 0) {
      slot[QBLK * D_DIM + row]        = mrow;
      slot[QBLK * D_DIM + QBLK + row] = lt;
    }
  }
}

__global__ __launch_bounds__(256, 4) void fattn_merge(
    const float* __restrict__ Ws, float* __restrict__ Og, int nchunk)
{
  const int qbi = blockIdx.x;
  const int Qb  = qbi & (NQB - 1);
  const int b   = qbi >> 5;
  const int tid = threadIdx.x;
  const int r   = tid >> 1;              // q row within 128-block
  const int d0  = (tid & 1) << 5;        // 32 d-elems per thread

  const int ntt = 2 * Qb + 2;
  const int cw  = (ntt + nchunk - 1) / nchunk;
  const int nvalid = (ntt + cw - 1) / cw;

  const float* base = Ws + (size_t)qbi * nchunk * SLOT_F;

  float mstar = -INFINITY;
  for (int ci = 0; ci < nvalid; ++ci)
    mstar = fmaxf(mstar, base[(size_t)ci * SLOT_F + QBLK * D_DIM + r]);

  float lsum = 0.f;
  float o[32];
  #pragma unroll
  for (int k = 0; k < 32; ++k) o[k] = 0.f;

  for (int ci = 0; ci < nvalid; ++ci) {
    const float* slot = base + (size_t)ci * SLOT_F;
    const float wgt = __expf(slot[QBLK * D_DIM + r] - mstar);
    lsum += wgt * slot[QBLK * D_DIM + QBLK + r];
    #pragma unroll
    for (int k = 0; k < 8; ++k) {
      const float4 ov = *(const float4*)(slot + r * 64 + d0 + 4 * k);
      o[4 * k + 0] += wgt * ov.x;
      o[4 * k + 1] += wgt * ov.y;
      o[4 * k + 2] += wgt * ov.z;
      o[4 * k + 3] += wgt * ov.w;
    }
  }

  const float inv = 1.0f / lsum;
  float* op = Og + ((size_t)(b * S_LEN + Qb * QBLK + r)) * D_DIM + d0;
  #pragma unroll
  for (int k = 0; k < 8; ++k) {
    float4 ov;
    ov.x = o[4 * k + 0] * inv;
    ov.y = o[4 * k + 1] * inv;
    ov.z = o[4 * k + 2] * inv;
    ov.w = o[4 * k + 3] * inv;
    *(float4*)(op + 4 * k) = ov;
  }
}

extern "C" void kernel_launch(void* const* d_in, const int* in_sizes, int n_in,
                              void* d_out, int out_size, void* d_ws, size_t ws_size,
                              hipStream_t stream) {
  const float* Q = (const float*)d_in[0];
  const float* K = (const float*)d_in[1];
  const float* V = (const float*)d_in[2];
  const unsigned char* P = (const unsigned char*)d_in[3];
  float* O  = (float*)d_out;
  float* Ws = (float*)d_ws;

  const size_t slot_bytes = (size_t)SLOT_F * 4;
  const size_t nqb_total  = (size_t)NBATCH * NQB;   // 128
  int nchunk = 1;
  if      (ws_size >= nqb_total * 8 * slot_bytes) nchunk = 8;
  else if (ws_size >= nqb_total * 4 * slot_bytes) nchunk = 4;
  else if (ws_size >= nqb_total * 2 * slot_bytes) nchunk = 2;

  dim3 grid(NBATCH * NQB * nchunk);
  dim3 block(256);
  hipLaunchKernelGGL(fattn_partial, grid, block, 0, stream, Q, K, V, P, O, Ws, nchunk);
  if (nchunk > 1) {
    dim3 mgrid(NBATCH * NQB);
    hipLaunchKernelGGL(fattn_merge, mgrid, block, 0, stream, Ws, O, nchunk);
  }
}